// Round 7
// baseline (314.046 us; speedup 1.0000x reference)
//
#include <hip/hip_runtime.h>
#include <math.h>

#define B_ 8
#define LP_ 64
#define LS_ 512
#define L_ 576
#define D_ 768
#define H_ 12
#define HD_ 64
#define V_ 50257
#define TOPK_ 10
#define CHUNKS_ 64
#define CHUNK_SZ_ 786  // ceil(V_/CHUNKS_); 64*786 = 50304 >= 50257
#define NVB_ 786       // ceil(V_/64) sim v-blocks

#define M_QKV 4608   // B_*L_
#define N_QKV 2304   // 3*D_
#define K_QKV 768

typedef __attribute__((ext_vector_type(8))) short bhalf8;
typedef __attribute__((ext_vector_type(4))) float floatx4;

#define GLOAD16(gptr, lptr)                                              \
  __builtin_amdgcn_global_load_lds(                                      \
      (const __attribute__((address_space(1))) unsigned int*)(gptr),     \
      (__attribute__((address_space(3))) unsigned int*)(lptr), 16, 0, 0)

// ---------------------------------------------------------------------------
// bf16 hi/lo split: x = hi + lo, hi = RNE-bf16(x), lo = RNE-bf16(x - hi).
// ---------------------------------------------------------------------------
__device__ inline void bf16split(float f, unsigned short& h, unsigned short& lo) {
  unsigned int u = __float_as_uint(f);
  unsigned short hb = (unsigned short)((u + 0x7FFFu + ((u >> 16) & 1u)) >> 16);
  float hf = __uint_as_float(((unsigned int)hb) << 16);
  float lf = f - hf;
  unsigned int ul = __float_as_uint(lf);
  unsigned short lb = (unsigned short)((ul + 0x7FFFu + ((ul >> 16) & 1u)) >> 16);
  h = hb; lo = lb;
}

// ---------------------------------------------------------------------------
// Kernel 0: build Ahi/Alo (x = concat(prompt,enc)) and Bhi/Blo (= Wqkv).
// ---------------------------------------------------------------------------
__global__ __launch_bounds__(256) void convert_split(
    const float* __restrict__ prompt, const float* __restrict__ enc,
    const float* __restrict__ Wqkv,
    unsigned short* __restrict__ Ahi, unsigned short* __restrict__ Alo,
    unsigned short* __restrict__ Bhi, unsigned short* __restrict__ Blo) {
  const int NA4 = M_QKV * K_QKV / 4;  // 884736
  const int NB4 = N_QKV * K_QKV / 4;  // 442368
  int i = blockIdx.x * 256 + threadIdx.x;
  if (i >= NA4 + NB4) return;
  const float* src;
  unsigned short *dh, *dl;
  int row, c4;
  if (i < NA4) {
    row = i / (K_QKV / 4);
    c4 = (i - row * (K_QKV / 4)) * 4;
    int b = row / L_, ll = row - (row / L_) * L_;
    src = (ll < LP_) ? (prompt + ((size_t)b * LP_ + ll) * D_ + c4)
                     : (enc + ((size_t)b * LS_ + (ll - LP_)) * D_ + c4);
    dh = Ahi + (size_t)row * K_QKV + c4;
    dl = Alo + (size_t)row * K_QKV + c4;
  } else {
    int j = i - NA4;
    row = j / (K_QKV / 4);
    c4 = (j - row * (K_QKV / 4)) * 4;
    src = Wqkv + (size_t)row * K_QKV + c4;
    dh = Bhi + (size_t)row * K_QKV + c4;
    dl = Blo + (size_t)row * K_QKV + c4;
  }
  float4 v = *(const float4*)src;
  ushort4 hv, lv;
  bf16split(v.x, hv.x, lv.x);
  bf16split(v.y, hv.y, lv.y);
  bf16split(v.z, hv.z, lv.z);
  bf16split(v.w, hv.w, lv.w);
  *(ushort4*)dh = hv;
  *(ushort4*)dl = lv;
}

// ---------------------------------------------------------------------------
// Kernel 1: QKV projection, split-bf16 MFMA, fused K-pass, 2-phase LDS
// double-buffer: stage tile kt+1 into buf^1 BEFORE computing tile kt; one
// barrier per step (implicit vmcnt(0) drain lands after ~400cy of compute).
// ---------------------------------------------------------------------------
__global__ __launch_bounds__(256) void qkv_mfma(
    const unsigned short* __restrict__ Ahi, const unsigned short* __restrict__ Alo,
    const unsigned short* __restrict__ Bhi, const unsigned short* __restrict__ Blo,
    unsigned short* __restrict__ Qhi, unsigned short* __restrict__ Qlo,
    unsigned short* __restrict__ Khi, unsigned short* __restrict__ Klo,
    float* __restrict__ Vv) {
  __shared__ unsigned short Ath[2][128 * 32];  // 8 KB each buffer
  __shared__ unsigned short Atl[2][128 * 32];
  __shared__ unsigned short Bth[2][128 * 32];
  __shared__ unsigned short Btl[2][128 * 32];  // total 64 KB
  // XCD-aware remap: grid 648 = 8 XCDs x 81 contiguous tiles
  const int flat = blockIdx.x;
  const int swz = (flat & 7) * 81 + (flat >> 3);
  const int bx = swz % 18, by = swz / 18;
  const int n0 = bx * 128, m0 = by * 128;
  const int tid = threadIdx.x;
  const int l = tid & 63;
  const int w = tid >> 6;          // wave 0..3
  const int wm = w >> 1, wn = w & 1;

  floatx4 acc[4][4];
#pragma unroll
  for (int i = 0; i < 4; ++i)
#pragma unroll
    for (int j = 0; j < 4; ++j) acc[i][j] = (floatx4){0.f, 0.f, 0.f, 0.f};

  const int r4 = l >> 2;
  const int cs = (l & 3) ^ ((l >> 3) & 3);   // pre-swizzled source chunk
  const int lm = l & 15;                     // fragment row/col within 16
  const int lk = l >> 4;                     // fragment k-group 0..3
  const int cb = lk ^ ((lm >> 1) & 3);       // stored chunk for frag reads

#define QKV_STAGE(kt_, buf_)                                                   \
  {                                                                            \
    const int kk0_ = (kt_) * 32;                                               \
    _Pragma("unroll")                                                          \
    for (int i_ = 0; i_ < 2; ++i_) {                                           \
      const int row_ = w * 32 + i_ * 16;                                       \
      const size_t ga_ = (size_t)(m0 + row_ + r4) * K_QKV + kk0_ + cs * 8;     \
      const size_t gb_ = (size_t)(n0 + row_ + r4) * K_QKV + kk0_ + cs * 8;     \
      GLOAD16(Ahi + ga_, &Ath[buf_][row_ * 32]);                               \
      GLOAD16(Alo + ga_, &Atl[buf_][row_ * 32]);                               \
      GLOAD16(Bhi + gb_, &Bth[buf_][row_ * 32]);                               \
      GLOAD16(Blo + gb_, &Btl[buf_][row_ * 32]);                               \
    }                                                                          \
  }

  QKV_STAGE(0, 0);
  __syncthreads();  // tile 0 visible
  int cur = 0;
  for (int kt = 0; kt < 24; ++kt) {
    if (kt + 1 < 24) QKV_STAGE(kt + 1, cur ^ 1);  // in flight during compute

    bhalf8 ah[4], al[4], bh8[4], bl8[4];
#pragma unroll
    for (int f = 0; f < 4; ++f) {
      const int ma = wm * 64 + f * 16 + lm;
      const int oa = ma * 32 + cb * 8;
      ah[f] = *(const bhalf8*)&Ath[cur][oa];
      al[f] = *(const bhalf8*)&Atl[cur][oa];
      const int nb = wn * 64 + f * 16 + lm;
      const int ob = nb * 32 + cb * 8;
      bh8[f] = *(const bhalf8*)&Bth[cur][ob];
      bl8[f] = *(const bhalf8*)&Btl[cur][ob];
    }
#pragma unroll
    for (int fm = 0; fm < 4; ++fm)
#pragma unroll
      for (int fn = 0; fn < 4; ++fn) {
        acc[fm][fn] = __builtin_amdgcn_mfma_f32_16x16x32_bf16(
            ah[fm], bh8[fn], acc[fm][fn], 0, 0, 0);
        acc[fm][fn] = __builtin_amdgcn_mfma_f32_16x16x32_bf16(
            al[fm], bh8[fn], acc[fm][fn], 0, 0, 0);
        acc[fm][fn] = __builtin_amdgcn_mfma_f32_16x16x32_bf16(
            ah[fm], bl8[fn], acc[fm][fn], 0, 0, 0);
      }
    __syncthreads();  // drains kt+1 loads; protects buf[cur] for overwrite
    cur ^= 1;
  }

  // C write: row m = lk*4 + j, col n = lm within each 16x16 fragment.
#pragma unroll
  for (int fm = 0; fm < 4; ++fm) {
#pragma unroll
    for (int fn = 0; fn < 4; ++fn) {
#pragma unroll
      for (int j = 0; j < 4; ++j) {
        int m = m0 + wm * 64 + fm * 16 + lk * 4 + j;
        int n = n0 + wn * 64 + fn * 16 + lm;
        int b = m / L_;
        int ll = m - b * L_;
        int part = n / D_;
        int rem = n - part * D_;
        int h = rem >> 6, e = rem & 63;
        size_t idx = (((size_t)b * H_ + h) * L_ + ll) * HD_ + e;
        float val = acc[fm][fn][j];
        if (part == 2) {
          Vv[idx] = val;
        } else {
          unsigned short hv, lv;
          bf16split(val, hv, lv);
          if (part == 0) { Qhi[idx] = hv; Qlo[idx] = lv; }
          else           { Khi[idx] = hv; Klo[idx] = lv; }
        }
      }
    }
  }
#undef QKV_STAGE
}

// ---------------------------------------------------------------------------
// Kernel 2: attention column sums via split-bf16 MFMA, K-tile double-buffer.
// ---------------------------------------------------------------------------
__global__ __launch_bounds__(256, 2) void attn_mfma(
    const unsigned short* __restrict__ Qhi, const unsigned short* __restrict__ Qlo,
    const unsigned short* __restrict__ Khi, const unsigned short* __restrict__ Klo,
    float* __restrict__ c) {
  __shared__ unsigned short Qh[64 * 64], Ql[64 * 64];      // 8 KB each
  __shared__ unsigned short Kh[2][64 * 64], Kl[2][64 * 64];  // 32 KB
  __shared__ float c_lds[L_];
  const int qt = blockIdx.x;   // 0..8
  const int bh = blockIdx.y;   // 0..95
  const int tid = threadIdx.x;
  const int w = tid >> 6, l = tid & 63;
  const int lm = l & 15, lk = l >> 4;
  const int r8 = l >> 3;
  const int cs = (l & 7) ^ r8;

  for (int i = tid; i < L_; i += 256) c_lds[i] = 0.f;

#define ATTN_STAGE_K(kt_, buf_)                                                \
  {                                                                            \
    const size_t kb_ = ((size_t)bh * L_ + (kt_) * 64) * HD_;                   \
    _Pragma("unroll")                                                          \
    for (int i_ = 0; i_ < 2; ++i_) {                                           \
      int row_ = w * 16 + i_ * 8;                                              \
      GLOAD16(Khi + kb_ + (size_t)(row_ + r8) * HD_ + cs * 8,                  \
              &Kh[buf_][row_ * 64]);                                           \
      GLOAD16(Klo + kb_ + (size_t)(row_ + r8) * HD_ + cs * 8,                  \
              &Kl[buf_][row_ * 64]);                                           \
    }                                                                          \
  }

  {  // stage Q tile + K tile 0 together
    const size_t gbase = ((size_t)bh * L_ + qt * 64) * HD_;
#pragma unroll
    for (int i = 0; i < 2; ++i) {
      int row = w * 16 + i * 8;
      GLOAD16(Qhi + gbase + (size_t)(row + r8) * HD_ + cs * 8, &Qh[row * 64]);
      GLOAD16(Qlo + gbase + (size_t)(row + r8) * HD_ + cs * 8, &Ql[row * 64]);
    }
  }
  ATTN_STAGE_K(0, 0);
  __syncthreads();  // Q + K0 visible (drains vmcnt)

  floatx4 p[9][4];
#pragma unroll
  for (int kt = 0; kt < 9; ++kt)
#pragma unroll
    for (int fn = 0; fn < 4; ++fn) p[kt][fn] = (floatx4){0.f, 0.f, 0.f, 0.f};
  float zpart[4] = {0.f, 0.f, 0.f, 0.f};

  int cur = 0;
#pragma unroll
  for (int kt = 0; kt < 9; ++kt) {
    if (kt + 1 < 9) ATTN_STAGE_K(kt + 1, cur ^ 1);
#pragma unroll
    for (int s = 0; s < 2; ++s) {
      const int ma = w * 16 + lm;
      const int ca = (s * 4 + lk) ^ (ma & 7);
      bhalf8 ah = *(const bhalf8*)&Qh[ma * 64 + ca * 8];
      bhalf8 al = *(const bhalf8*)&Ql[ma * 64 + ca * 8];
#pragma unroll
      for (int fn = 0; fn < 4; ++fn) {
        const int nb = fn * 16 + lm;
        const int cb2 = (s * 4 + lk) ^ (nb & 7);
        bhalf8 bh8 = *(const bhalf8*)&Kh[cur][nb * 64 + cb2 * 8];
        bhalf8 bl8 = *(const bhalf8*)&Kl[cur][nb * 64 + cb2 * 8];
        p[kt][fn] = __builtin_amdgcn_mfma_f32_16x16x32_bf16(ah, bh8, p[kt][fn], 0, 0, 0);
        p[kt][fn] = __builtin_amdgcn_mfma_f32_16x16x32_bf16(al, bh8, p[kt][fn], 0, 0, 0);
        p[kt][fn] = __builtin_amdgcn_mfma_f32_16x16x32_bf16(ah, bl8, p[kt][fn], 0, 0, 0);
      }
    }
#pragma unroll
    for (int fn = 0; fn < 4; ++fn)
#pragma unroll
      for (int j = 0; j < 4; ++j) {
        float e = __expf(p[kt][fn][j] * 0.125f);
        p[kt][fn][j] = e;
        zpart[j] += e;
      }
    __syncthreads();  // drains kt+1 loads; protects buf[cur] for overwrite
    cur ^= 1;
  }

  float invz[4];
#pragma unroll
  for (int j = 0; j < 4; ++j) {
    float z = zpart[j];
    z += __shfl_xor(z, 1);
    z += __shfl_xor(z, 2);
    z += __shfl_xor(z, 4);
    z += __shfl_xor(z, 8);
    invz[j] = 1.f / z;
  }

#pragma unroll
  for (int kt = 0; kt < 9; ++kt)
#pragma unroll
    for (int fn = 0; fn < 4; ++fn) {
      float cp = p[kt][fn][0] * invz[0] + p[kt][fn][1] * invz[1] +
                 p[kt][fn][2] * invz[2] + p[kt][fn][3] * invz[3];
      cp += __shfl_xor(cp, 16);
      cp += __shfl_xor(cp, 32);
      if (lk == 0) atomicAdd(&c_lds[kt * 64 + fn * 16 + lm], cp);
    }
  __syncthreads();
  for (int i = tid; i < L_; i += 256)
    atomicAdd(&c[(size_t)bh * L_ + i], c_lds[i]);
#undef ATTN_STAGE_K
}

// ---------------------------------------------------------------------------
// Kernel 3: t[b, h*64+e] = sum_k c[b,h,k] * V[b,h,k,e]
// ---------------------------------------------------------------------------
__global__ void cv_kernel(const float* __restrict__ c,
                          const float* __restrict__ Vv,
                          float* __restrict__ t) {
  const int bh = blockIdx.x;
  const int e = threadIdx.x;
  const float* cb = c + (size_t)bh * L_;
  const float* Vb = Vv + (size_t)bh * L_ * HD_;
  float acc = 0.f;
  for (int k = 0; k < L_; ++k) acc = fmaf(cb[k], Vb[(size_t)k * HD_ + e], acc);
  int b = bh / H_, h = bh - (bh / H_) * H_;
  t[(size_t)b * D_ + h * HD_ + e] = acc;
}

// ---------------------------------------------------------------------------
// Kernel 4: s[b,d] = sum_d' t[b,d'] * Wproj[d,d'] + L*bproj[d]
// ---------------------------------------------------------------------------
__global__ __launch_bounds__(768) void proj_kernel(
    const float* __restrict__ t, const float* __restrict__ Wp,
    const float* __restrict__ bp, float* __restrict__ s) {
  __shared__ float tl[768];
  const int b = blockIdx.x, d = threadIdx.x;
  tl[d] = t[(size_t)b * D_ + d];
  __syncthreads();
  float acc = (float)L_ * bp[d];
  const float* wrow = Wp + (size_t)d * D_;
  for (int dp = 0; dp < D_; ++dp) acc = fmaf(tl[dp], wrow[dp], acc);
  s[(size_t)b * D_ + d] = acc;
}

// ---------------------------------------------------------------------------
// Kernel 5: sim[b,v] = sum_d s[b,d] * word_emd[v,d]. Memory-bound: streams
// 154 MB of w. 786 blocks x 64 v-rows, T14 async-stage split.
// ---------------------------------------------------------------------------
__global__ __launch_bounds__(256) void sim_kernel(
    const float* __restrict__ s, const float* __restrict__ w,
    float* __restrict__ sim) {
  __shared__ float sl[8][768];   // 24 KB
  __shared__ float wl[32][65];   // 8.125 KB, [d-in-chunk][row]
  const int tid = threadIdx.x;
  const int v0 = blockIdx.x * 64;

  for (int i = tid; i < 1536; i += 256)
    ((float4*)&sl[0][0])[i] = ((const float4*)s)[i];

  const int lr0 = tid >> 3;            // rows 0..31
  const int lr1 = lr0 + 32;            // rows 32..63
  const int lc4 = (tid & 7) << 2;      // 0,4,...,28
  int vr0 = v0 + lr0; if (vr0 >= V_) vr0 = V_ - 1;
  int vr1 = v0 + lr1; if (vr1 >= V_) vr1 = V_ - 1;
  const float* wp0 = w + (size_t)vr0 * D_ + lc4;
  const float* wp1 = w + (size_t)vr1 * D_ + lc4;

  float4 stg0 = *(const float4*)(wp0);
  float4 stg1 = *(const float4*)(wp1);

  const int cr = tid & 63;   // compute row (wave = one q)
  const int q = tid >> 6;    // d-quarter within chunk
  float acc[8] = {};

  for (int ch = 0; ch < 24; ++ch) {
    __syncthreads();  // previous chunk fully read
    wl[lc4 + 0][lr0] = stg0.x; wl[lc4 + 1][lr0] = stg0.y;
    wl[lc4 + 2][lr0] = stg0.z; wl[lc4 + 3][lr0] = stg0.w;
    wl[lc4 + 0][lr1] = stg1.x; wl[lc4 + 1][lr1] = stg1.y;
    wl[lc4 + 2][lr1] = stg1.z; wl[lc4 + 3][lr1] = stg1.w;
    __syncthreads();  // tile visible
    if (ch + 1 < 24) {
      stg0 = *(const float4*)(wp0 + (ch + 1) * 32);
      stg1 = *(const float4*)(wp1 + (ch + 1) * 32);
    }
    const int d0 = ch * 32;
#pragma unroll
    for (int g = 0; g < 2; ++g) {
      const int dd = q * 8 + g * 4;
      float w0 = wl[dd + 0][cr], w1 = wl[dd + 1][cr];
      float w2 = wl[dd + 2][cr], w3 = wl[dd + 3][cr];
#pragma unroll
      for (int b = 0; b < 8; ++b) {
        float4 sv = *(const float4*)&sl[b][d0 + dd];
        acc[b] = fmaf(w0, sv.x, acc[b]);
        acc[b] = fmaf(w1, sv.y, acc[b]);
        acc[b] = fmaf(w2, sv.z, acc[b]);
        acc[b] = fmaf(w3, sv.w, acc[b]);
      }
    }
  }

  __syncthreads();
  float* red = &wl[0][0];
  float4* rp = (float4*)&red[(q * 64 + cr) * 8];
  rp[0] = make_float4(acc[0], acc[1], acc[2], acc[3]);
  rp[1] = make_float4(acc[4], acc[5], acc[6], acc[7]);
  __syncthreads();
#pragma unroll
  for (int u = 0; u < 2; ++u) {
    int o = tid * 2 + u;
    int r = o >> 3, b = o & 7;
    float sum = red[(0 * 64 + r) * 8 + b] + red[(1 * 64 + r) * 8 + b] +
                red[(2 * 64 + r) * 8 + b] + red[(3 * 64 + r) * 8 + b];
    int v = v0 + r;
    if (v < V_) sim[(size_t)b * V_ + v] = sum;
  }
}

// ---------------------------------------------------------------------------
// Kernel 6a: per-chunk local top-10.
// ---------------------------------------------------------------------------
__global__ __launch_bounds__(256) void topk_stage1(
    const float* __restrict__ sim, float* __restrict__ cv,
    int* __restrict__ ci) {
  __shared__ float vals[CHUNK_SZ_];
  __shared__ float bv[256];
  __shared__ int bi[256];
  const int chunk = blockIdx.x, b = blockIdx.y, tid = threadIdx.x;
  const int base = chunk * CHUNK_SZ_;
  const float* row = sim + (size_t)b * V_;
  for (int i = tid; i < CHUNK_SZ_; i += 256) {
    int v = base + i;
    vals[i] = (v < V_) ? row[v] : -INFINITY;
  }
  __syncthreads();
  for (int k = 0; k < TOPK_; ++k) {
    float best = -INFINITY;
    int besti = CHUNK_SZ_;
    for (int i = tid; i < CHUNK_SZ_; i += 256) {
      float x = vals[i];
      if (x > best) { best = x; besti = i; }
    }
    bv[tid] = best; bi[tid] = besti;
    __syncthreads();
    for (int off = 128; off > 0; off >>= 1) {
      if (tid < off) {
        float ov = bv[tid + off]; int oi = bi[tid + off];
        if (ov > bv[tid] || (ov == bv[tid] && oi < bi[tid])) {
          bv[tid] = ov; bi[tid] = oi;
        }
      }
      __syncthreads();
    }
    if (tid == 0) {
      int slot = (b * CHUNKS_ + chunk) * TOPK_ + k;
      cv[slot] = bv[0];
      ci[slot] = base + bi[0];
      if (bi[0] < CHUNK_SZ_) vals[bi[0]] = -INFINITY;
    }
    __syncthreads();
  }
}

// ---------------------------------------------------------------------------
// Kernel 6b: reduce 64 chunks x 10 candidates -> global top-10 per batch.
// ---------------------------------------------------------------------------
__global__ __launch_bounds__(256) void topk_stage2(
    const float* __restrict__ cv, const int* __restrict__ ci,
    int* __restrict__ topk) {
  const int NC = CHUNKS_ * TOPK_;  // 640
  __shared__ float vals[CHUNKS_ * TOPK_];
  __shared__ int gidx[CHUNKS_ * TOPK_];
  __shared__ float bv[256];
  __shared__ int bi[256];
  const int b = blockIdx.x, tid = threadIdx.x;
  for (int i = tid; i < NC; i += 256) {
    vals[i] = cv[(size_t)b * NC + i];
    gidx[i] = ci[(size_t)b * NC + i];
  }
  __syncthreads();
  for (int k = 0; k < TOPK_; ++k) {
    float best = -INFINITY;
    int bslot = NC;
    for (int i = tid; i < NC; i += 256) {
      float x = vals[i];
      if (x > best) { best = x; bslot = i; }
    }
    bv[tid] = best; bi[tid] = bslot;
    __syncthreads();
    for (int off = 128; off > 0; off >>= 1) {
      if (tid < off) {
        float ov = bv[tid + off]; int oi = bi[tid + off];
        if (ov > bv[tid] || (ov == bv[tid] && oi < bi[tid])) {
          bv[tid] = ov; bi[tid] = oi;
        }
      }
      __syncthreads();
    }
    if (tid == 0) {
      int slot = bi[0];
      topk[b * TOPK_ + k] = (slot < NC) ? gidx[slot] : 0;
      if (slot < NC) vals[slot] = -INFINITY;
    }
    __syncthreads();
  }
}

// ---------------------------------------------------------------------------
// Kernel 7: gather word_emd rows -> output [B, K, D]
// ---------------------------------------------------------------------------
__global__ void gather_kernel(const int* __restrict__ topk,
                              const float* __restrict__ w,
                              float* __restrict__ out) {
  const int bk = blockIdx.x;
  const int idx = topk[bk];
  const int t4 = threadIdx.x << 2;
  *(float4*)(out + (size_t)bk * D_ + t4) =
      *(const float4*)(w + (size_t)idx * D_ + t4);
}

extern "C" void kernel_launch(void* const* d_in, const int* in_sizes, int n_in,
                              void* d_out, int out_size, void* d_ws,
                              size_t ws_size, hipStream_t stream) {
  const float* prompt = (const float*)d_in[0];
  const float* enc    = (const float*)d_in[1];
  const float* wemd   = (const float*)d_in[2];
  const float* Wqkv   = (const float*)d_in[3];
  const float* Wproj  = (const float*)d_in[4];
  const float* bproj  = (const float*)d_in[5];
  float* out = (float*)d_out;

  float* ws = (float*)d_ws;
  const size_t QSZ = (size_t)B_ * H_ * L_ * HD_;  // 3,538,944
  float* Vv   = ws;                        // fp32 V
  float* c    = Vv + QSZ;                  // 96*576 = 55,296
  float* t    = c + (size_t)B_ * H_ * L_;  // 6144
  float* s    = t + (size_t)B_ * D_;       // 6144
  float* sim  = s + (size_t)B_ * D_;       // 8*50257 = 402,056
  float* cand_v = sim + (size_t)B_ * V_;   // 8*640 = 5120
  int* cand_i   = (int*)(cand_v + (size_t)B_ * CHUNKS_ * TOPK_);
  int* topk     = cand_i + (size_t)B_ * CHUNKS_ * TOPK_;
  unsigned short* Qhi = (unsigned short*)(topk + B_ * TOPK_ + 64);
  unsigned short* Qlo = Qhi + QSZ;
  unsigned short* Khi = Qlo + QSZ;
  unsigned short* Klo = Khi + QSZ;
  unsigned short* Ahi = Klo + QSZ;
  unsigned short* Alo = Ahi + (size_t)M_QKV * K_QKV;
  unsigned short* Bhi = Alo + (size_t)M_QKV * K_QKV;
  unsigned short* Blo = Bhi + (size_t)N_QKV * K_QKV;

  hipMemsetAsync(c, 0, (size_t)B_ * H_ * L_ * sizeof(float), stream);

  const int NCONV = (M_QKV * K_QKV + N_QKV * K_QKV) / 4;  // 1,327,104
  convert_split<<<(NCONV + 255) / 256, 256, 0, stream>>>(
      prompt, enc, Wqkv, Ahi, Alo, Bhi, Blo);
  qkv_mfma<<<648, 256, 0, stream>>>(
      Ahi, Alo, Bhi, Blo, Qhi, Qlo, Khi, Klo, Vv);
  attn_mfma<<<dim3(9, 96), 256, 0, stream>>>(Qhi, Qlo, Khi, Klo, c);
  cv_kernel<<<96, 64, 0, stream>>>(c, Vv, t);
  proj_kernel<<<8, 768, 0, stream>>>(t, Wproj, bproj, s);
  sim_kernel<<<NVB_, 256, 0, stream>>>(s, wemd, sim);
  topk_stage1<<<dim3(CHUNKS_, B_), 256, 0, stream>>>(sim, cand_v, cand_i);
  topk_stage2<<<B_, 256, 0, stream>>>(cand_v, cand_i, topk);
  gather_kernel<<<80, 192, 0, stream>>>(topk, wemd, out);
}

// Round 9
// 303.159 us; speedup vs baseline: 1.0359x; 1.0359x over previous
//
#include <hip/hip_runtime.h>
#include <math.h>

#define B_ 8
#define LP_ 64
#define LS_ 512
#define L_ 576
#define D_ 768
#define H_ 12
#define HD_ 64
#define V_ 50257
#define TOPK_ 10
#define CHUNKS_ 64
#define CHUNK_SZ_ 786  // ceil(V_/CHUNKS_); 64*786 = 50304 >= 50257

#define M_QKV 4608   // B_*L_
#define N_QKV 2304   // 3*D_
#define K_QKV 768

typedef __attribute__((ext_vector_type(8))) short bhalf8;
typedef __attribute__((ext_vector_type(4))) float floatx4;

#define GLOAD16(gptr, lptr)                                              \
  __builtin_amdgcn_global_load_lds(                                      \
      (const __attribute__((address_space(1))) unsigned int*)(gptr),     \
      (__attribute__((address_space(3))) unsigned int*)(lptr), 16, 0, 0)

// ---------------------------------------------------------------------------
// bf16 hi/lo split: x = hi + lo, hi = RNE-bf16(x), lo = RNE-bf16(x - hi).
// ---------------------------------------------------------------------------
__device__ inline void bf16split(float f, unsigned short& h, unsigned short& lo) {
  unsigned int u = __float_as_uint(f);
  unsigned short hb = (unsigned short)((u + 0x7FFFu + ((u >> 16) & 1u)) >> 16);
  float hf = __uint_as_float(((unsigned int)hb) << 16);
  float lf = f - hf;
  unsigned int ul = __float_as_uint(lf);
  unsigned short lb = (unsigned short)((ul + 0x7FFFu + ((ul >> 16) & 1u)) >> 16);
  h = hb; lo = lb;
}

// ---------------------------------------------------------------------------
// Kernel 0: build Ahi/Alo (x = concat(prompt,enc)) and Bhi/Blo (= Wqkv).
// ---------------------------------------------------------------------------
__global__ __launch_bounds__(256) void convert_split(
    const float* __restrict__ prompt, const float* __restrict__ enc,
    const float* __restrict__ Wqkv,
    unsigned short* __restrict__ Ahi, unsigned short* __restrict__ Alo,
    unsigned short* __restrict__ Bhi, unsigned short* __restrict__ Blo) {
  const int NA4 = M_QKV * K_QKV / 4;  // 884736
  const int NB4 = N_QKV * K_QKV / 4;  // 442368
  int i = blockIdx.x * 256 + threadIdx.x;
  if (i >= NA4 + NB4) return;
  const float* src;
  unsigned short *dh, *dl;
  int row, c4;
  if (i < NA4) {
    row = i / (K_QKV / 4);
    c4 = (i - row * (K_QKV / 4)) * 4;
    int b = row / L_, ll = row - (row / L_) * L_;
    src = (ll < LP_) ? (prompt + ((size_t)b * LP_ + ll) * D_ + c4)
                     : (enc + ((size_t)b * LS_ + (ll - LP_)) * D_ + c4);
    dh = Ahi + (size_t)row * K_QKV + c4;
    dl = Alo + (size_t)row * K_QKV + c4;
  } else {
    int j = i - NA4;
    row = j / (K_QKV / 4);
    c4 = (j - row * (K_QKV / 4)) * 4;
    src = Wqkv + (size_t)row * K_QKV + c4;
    dh = Bhi + (size_t)row * K_QKV + c4;
    dl = Blo + (size_t)row * K_QKV + c4;
  }
  float4 v = *(const float4*)src;
  ushort4 hv, lv;
  bf16split(v.x, hv.x, lv.x);
  bf16split(v.y, hv.y, lv.y);
  bf16split(v.z, hv.z, lv.z);
  bf16split(v.w, hv.w, lv.w);
  *(ushort4*)dh = hv;
  *(ushort4*)dl = lv;
}

// ---------------------------------------------------------------------------
// Kernel 1: QKV projection, split-bf16 MFMA, fused single K-pass (round-6
// structure: 32 KB LDS single buffer — measured best; dbuf regressed via
// occupancy loss). BK=32, 48 MFMA per barrier-pair per wave.
// ---------------------------------------------------------------------------
__global__ __launch_bounds__(256) void qkv_mfma(
    const unsigned short* __restrict__ Ahi, const unsigned short* __restrict__ Alo,
    const unsigned short* __restrict__ Bhi, const unsigned short* __restrict__ Blo,
    unsigned short* __restrict__ Qhi, unsigned short* __restrict__ Qlo,
    unsigned short* __restrict__ Khi, unsigned short* __restrict__ Klo,
    float* __restrict__ Vv) {
  __shared__ unsigned short Ath[128 * 32];  // 8 KB each
  __shared__ unsigned short Atl[128 * 32];
  __shared__ unsigned short Bth[128 * 32];
  __shared__ unsigned short Btl[128 * 32];
  const int flat = blockIdx.x;
  const int swz = (flat & 7) * 81 + (flat >> 3);  // 648 = 8 XCD x 81
  const int bx = swz % 18, by = swz / 18;
  const int n0 = bx * 128, m0 = by * 128;
  const int tid = threadIdx.x;
  const int l = tid & 63;
  const int w = tid >> 6;
  const int wm = w >> 1, wn = w & 1;

  floatx4 acc[4][4];
#pragma unroll
  for (int i = 0; i < 4; ++i)
#pragma unroll
    for (int j = 0; j < 4; ++j) acc[i][j] = (floatx4){0.f, 0.f, 0.f, 0.f};

  const int r4 = l >> 2;
  const int cs = (l & 3) ^ ((l >> 3) & 3);
  const int lm = l & 15;
  const int lk = l >> 4;
  const int cb = lk ^ ((lm >> 1) & 3);

  for (int kt = 0; kt < 24; ++kt) {
    const int kk0 = kt * 32;
    __syncthreads();
#pragma unroll
    for (int i = 0; i < 2; ++i) {
      const int row = w * 32 + i * 16;
      const size_t ga = (size_t)(m0 + row + r4) * K_QKV + kk0 + cs * 8;
      const size_t gb = (size_t)(n0 + row + r4) * K_QKV + kk0 + cs * 8;
      GLOAD16(Ahi + ga, &Ath[row * 32]);
      GLOAD16(Alo + ga, &Atl[row * 32]);
      GLOAD16(Bhi + gb, &Bth[row * 32]);
      GLOAD16(Blo + gb, &Btl[row * 32]);
    }
    __syncthreads();

    bhalf8 ah[4], al[4], bh8[4], bl8[4];
#pragma unroll
    for (int f = 0; f < 4; ++f) {
      const int ma = wm * 64 + f * 16 + lm;
      const int oa = ma * 32 + cb * 8;
      ah[f] = *(const bhalf8*)&Ath[oa];
      al[f] = *(const bhalf8*)&Atl[oa];
      const int nb = wn * 64 + f * 16 + lm;
      const int ob = nb * 32 + cb * 8;
      bh8[f] = *(const bhalf8*)&Bth[ob];
      bl8[f] = *(const bhalf8*)&Btl[ob];
    }
#pragma unroll
    for (int fm = 0; fm < 4; ++fm)
#pragma unroll
      for (int fn = 0; fn < 4; ++fn) {
        acc[fm][fn] = __builtin_amdgcn_mfma_f32_16x16x32_bf16(
            ah[fm], bh8[fn], acc[fm][fn], 0, 0, 0);
        acc[fm][fn] = __builtin_amdgcn_mfma_f32_16x16x32_bf16(
            al[fm], bh8[fn], acc[fm][fn], 0, 0, 0);
        acc[fm][fn] = __builtin_amdgcn_mfma_f32_16x16x32_bf16(
            ah[fm], bl8[fn], acc[fm][fn], 0, 0, 0);
      }
  }

#pragma unroll
  for (int fm = 0; fm < 4; ++fm) {
#pragma unroll
    for (int fn = 0; fn < 4; ++fn) {
#pragma unroll
      for (int j = 0; j < 4; ++j) {
        int m = m0 + wm * 64 + fm * 16 + lk * 4 + j;
        int n = n0 + wn * 64 + fn * 16 + lm;
        int b = m / L_;
        int ll = m - b * L_;
        int part = n / D_;
        int rem = n - part * D_;
        int h = rem >> 6, e = rem & 63;
        size_t idx = (((size_t)b * H_ + h) * L_ + ll) * HD_ + e;
        float val = acc[fm][fn][j];
        if (part == 2) {
          Vv[idx] = val;
        } else {
          unsigned short hv, lv;
          bf16split(val, hv, lv);
          if (part == 0) { Qhi[idx] = hv; Qlo[idx] = lv; }
          else           { Khi[idx] = hv; Klo[idx] = lv; }
        }
      }
    }
  }
}

// ---------------------------------------------------------------------------
// Kernel 2: attention column sums via split-bf16 MFMA (round-6 single-buffer).
// ---------------------------------------------------------------------------
__global__ __launch_bounds__(256, 2) void attn_mfma(
    const unsigned short* __restrict__ Qhi, const unsigned short* __restrict__ Qlo,
    const unsigned short* __restrict__ Khi, const unsigned short* __restrict__ Klo,
    float* __restrict__ c) {
  __shared__ unsigned short Qh[64 * 64], Ql[64 * 64];  // 8 KB each
  __shared__ unsigned short Kh[64 * 64], Kl[64 * 64];
  __shared__ float c_lds[L_];
  const int qt = blockIdx.x;   // 0..8
  const int bh = blockIdx.y;   // 0..95
  const int tid = threadIdx.x;
  const int w = tid >> 6, l = tid & 63;
  const int lm = l & 15, lk = l >> 4;
  const int r8 = l >> 3;
  const int cs = (l & 7) ^ r8;

  for (int i = tid; i < L_; i += 256) c_lds[i] = 0.f;

  {
    const size_t gbase = ((size_t)bh * L_ + qt * 64) * HD_;
#pragma unroll
    for (int i = 0; i < 2; ++i) {
      int row = w * 16 + i * 8;
      GLOAD16(Qhi + gbase + (size_t)(row + r8) * HD_ + cs * 8, &Qh[row * 64]);
      GLOAD16(Qlo + gbase + (size_t)(row + r8) * HD_ + cs * 8, &Ql[row * 64]);
    }
  }

  floatx4 p[9][4];
#pragma unroll
  for (int kt = 0; kt < 9; ++kt)
#pragma unroll
    for (int fn = 0; fn < 4; ++fn) p[kt][fn] = (floatx4){0.f, 0.f, 0.f, 0.f};
  float zpart[4] = {0.f, 0.f, 0.f, 0.f};

#pragma unroll
  for (int kt = 0; kt < 9; ++kt) {
    __syncthreads();
    const size_t kb = ((size_t)bh * L_ + kt * 64) * HD_;
#pragma unroll
    for (int i = 0; i < 2; ++i) {
      int row = w * 16 + i * 8;
      GLOAD16(Khi + kb + (size_t)(row + r8) * HD_ + cs * 8, &Kh[row * 64]);
      GLOAD16(Klo + kb + (size_t)(row + r8) * HD_ + cs * 8, &Kl[row * 64]);
    }
    __syncthreads();
#pragma unroll
    for (int s = 0; s < 2; ++s) {
      const int ma = w * 16 + lm;
      const int ca = (s * 4 + lk) ^ (ma & 7);
      bhalf8 ah = *(const bhalf8*)&Qh[ma * 64 + ca * 8];
      bhalf8 al = *(const bhalf8*)&Ql[ma * 64 + ca * 8];
#pragma unroll
      for (int fn = 0; fn < 4; ++fn) {
        const int nb = fn * 16 + lm;
        const int cb2 = (s * 4 + lk) ^ (nb & 7);
        bhalf8 bh8 = *(const bhalf8*)&Kh[nb * 64 + cb2 * 8];
        bhalf8 bl8 = *(const bhalf8*)&Kl[nb * 64 + cb2 * 8];
        p[kt][fn] = __builtin_amdgcn_mfma_f32_16x16x32_bf16(ah, bh8, p[kt][fn], 0, 0, 0);
        p[kt][fn] = __builtin_amdgcn_mfma_f32_16x16x32_bf16(al, bh8, p[kt][fn], 0, 0, 0);
        p[kt][fn] = __builtin_amdgcn_mfma_f32_16x16x32_bf16(ah, bl8, p[kt][fn], 0, 0, 0);
      }
    }
#pragma unroll
    for (int fn = 0; fn < 4; ++fn)
#pragma unroll
      for (int j = 0; j < 4; ++j) {
        float e = __expf(p[kt][fn][j] * 0.125f);
        p[kt][fn][j] = e;
        zpart[j] += e;
      }
  }

  float invz[4];
#pragma unroll
  for (int j = 0; j < 4; ++j) {
    float z = zpart[j];
    z += __shfl_xor(z, 1);
    z += __shfl_xor(z, 2);
    z += __shfl_xor(z, 4);
    z += __shfl_xor(z, 8);
    invz[j] = 1.f / z;
  }

#pragma unroll
  for (int kt = 0; kt < 9; ++kt)
#pragma unroll
    for (int fn = 0; fn < 4; ++fn) {
      float cp = p[kt][fn][0] * invz[0] + p[kt][fn][1] * invz[1] +
                 p[kt][fn][2] * invz[2] + p[kt][fn][3] * invz[3];
      cp += __shfl_xor(cp, 16);
      cp += __shfl_xor(cp, 32);
      if (lk == 0) atomicAdd(&c_lds[kt * 64 + fn * 16 + lm], cp);
    }
  __syncthreads();
  for (int i = tid; i < L_; i += 256)
    atomicAdd(&c[(size_t)bh * L_ + i], c_lds[i]);
}

// ---------------------------------------------------------------------------
// Kernel 3: t[b, h*64+e] = sum_k c[b,h,k] * V[b,h,k,e]
// ---------------------------------------------------------------------------
__global__ void cv_kernel(const float* __restrict__ c,
                          const float* __restrict__ Vv,
                          float* __restrict__ t) {
  const int bh = blockIdx.x;
  const int e = threadIdx.x;
  const float* cb = c + (size_t)bh * L_;
  const float* Vb = Vv + (size_t)bh * L_ * HD_;
  float acc = 0.f;
  for (int k = 0; k < L_; ++k) acc = fmaf(cb[k], Vb[(size_t)k * HD_ + e], acc);
  int b = bh / H_, h = bh - (bh / H_) * H_;
  t[(size_t)b * D_ + h * HD_ + e] = acc;
}

// ---------------------------------------------------------------------------
// Kernel 4: s[b,d] = sum_d' t[b,d'] * Wproj[d,d'] + L*bproj[d]
// ---------------------------------------------------------------------------
__global__ __launch_bounds__(768) void proj_kernel(
    const float* __restrict__ t, const float* __restrict__ Wp,
    const float* __restrict__ bp, float* __restrict__ s) {
  __shared__ float tl[768];
  const int b = blockIdx.x, d = threadIdx.x;
  tl[d] = t[(size_t)b * D_ + d];
  __syncthreads();
  float acc = (float)L_ * bp[d];
  const float* wrow = Wp + (size_t)d * D_;
  for (int dp = 0; dp < D_; ++dp) acc = fmaf(tl[dp], wrow[dp], acc);
  s[(size_t)b * D_ + d] = acc;
}

// ---------------------------------------------------------------------------
// Kernel 5: sim[b,v] = sum_d s[b,d] * word_emd[v,d]. Pure streaming: w has
// zero reuse -> NO w staging. s reordered in LDS: slot (k,p) holds the 32
// floats s[b][k*64+p*4+j] (j<4,b<8) contiguously; row stride 36 floats.
// Each 16-lane group streams 2 v-rows with coalesced float4 loads; acc in
// regs; shfl_xor reduce over the 16 lanes. No barriers in main loop.
// ---------------------------------------------------------------------------
__global__ __launch_bounds__(256) void sim_kernel(
    const float* __restrict__ s, const float* __restrict__ w,
    float* __restrict__ sim) {
  __shared__ float s2[192 * 36];  // 27 KB
  const int tid = threadIdx.x;
  for (int e = tid; e < 6144; e += 256) {
    int b = e / 768;           // FIXED: stride 768 (was e>>9 / e&767 — wrong)
    int d = e - b * 768;
    int k = d >> 6, pj = d & 63;
    int p = pj >> 2, j = pj & 3;
    s2[(k * 16 + p) * 36 + j * 8 + b] = s[e];
  }
  __syncthreads();

  const int wv = tid >> 6, l = tid & 63;
  const int g = l >> 4, p = l & 15;
  const int r0 = blockIdx.x * 64;

#pragma unroll
  for (int it = 0; it < 2; ++it) {
    const int base = r0 + it * 32 + wv * 8;
    const int rA = base + g, rB = base + g + 4;
    const int cA = (rA < V_) ? rA : (V_ - 1);
    const int cB = (rB < V_) ? rB : (V_ - 1);
    const float* wpA = w + (size_t)cA * D_ + p * 4;
    const float* wpB = w + (size_t)cB * D_ + p * 4;
    float accA[8] = {}, accB[8] = {};
    float4 wa = *(const float4*)(wpA);
    float4 wb = *(const float4*)(wpB);
#pragma unroll
    for (int k = 0; k < 12; ++k) {
      float4 cwa = wa, cwb = wb;
      if (k + 1 < 12) {  // prefetch next d-step while computing this one
        wa = *(const float4*)(wpA + (k + 1) * 64);
        wb = *(const float4*)(wpB + (k + 1) * 64);
      }
      const float* sb = &s2[(k * 16 + p) * 36];
      float4 sj[8];
#pragma unroll
      for (int jj = 0; jj < 8; ++jj) sj[jj] = *(const float4*)(sb + jj * 4);
      float ca[4] = {cwa.x, cwa.y, cwa.z, cwa.w};
      float cb[4] = {cwb.x, cwb.y, cwb.z, cwb.w};
#pragma unroll
      for (int j = 0; j < 4; ++j) {
        accA[0] = fmaf(ca[j], sj[2 * j].x, accA[0]);
        accA[1] = fmaf(ca[j], sj[2 * j].y, accA[1]);
        accA[2] = fmaf(ca[j], sj[2 * j].z, accA[2]);
        accA[3] = fmaf(ca[j], sj[2 * j].w, accA[3]);
        accA[4] = fmaf(ca[j], sj[2 * j + 1].x, accA[4]);
        accA[5] = fmaf(ca[j], sj[2 * j + 1].y, accA[5]);
        accA[6] = fmaf(ca[j], sj[2 * j + 1].z, accA[6]);
        accA[7] = fmaf(ca[j], sj[2 * j + 1].w, accA[7]);
        accB[0] = fmaf(cb[j], sj[2 * j].x, accB[0]);
        accB[1] = fmaf(cb[j], sj[2 * j].y, accB[1]);
        accB[2] = fmaf(cb[j], sj[2 * j].z, accB[2]);
        accB[3] = fmaf(cb[j], sj[2 * j].w, accB[3]);
        accB[4] = fmaf(cb[j], sj[2 * j + 1].x, accB[4]);
        accB[5] = fmaf(cb[j], sj[2 * j + 1].y, accB[5]);
        accB[6] = fmaf(cb[j], sj[2 * j + 1].z, accB[6]);
        accB[7] = fmaf(cb[j], sj[2 * j + 1].w, accB[7]);
      }
    }
    // reduce over the 16 lanes of the group (xor masks 1,2,4,8 stay in-group)
#pragma unroll
    for (int off = 1; off < 16; off <<= 1) {
#pragma unroll
      for (int b = 0; b < 8; ++b) {
        accA[b] += __shfl_xor(accA[b], off);
        accB[b] += __shfl_xor(accB[b], off);
      }
    }
    if (p == 0) {
#pragma unroll
      for (int b = 0; b < 8; ++b) {
        if (rA < V_) sim[(size_t)b * V_ + rA] = accA[b];
        if (rB < V_) sim[(size_t)b * V_ + rB] = accB[b];
      }
    }
  }
}

// ---------------------------------------------------------------------------
// Kernel 6a: per-chunk local top-10.
// ---------------------------------------------------------------------------
__global__ __launch_bounds__(256) void topk_stage1(
    const float* __restrict__ sim, float* __restrict__ cv,
    int* __restrict__ ci) {
  __shared__ float vals[CHUNK_SZ_];
  __shared__ float bv[256];
  __shared__ int bi[256];
  const int chunk = blockIdx.x, b = blockIdx.y, tid = threadIdx.x;
  const int base = chunk * CHUNK_SZ_;
  const float* row = sim + (size_t)b * V_;
  for (int i = tid; i < CHUNK_SZ_; i += 256) {
    int v = base + i;
    vals[i] = (v < V_) ? row[v] : -INFINITY;
  }
  __syncthreads();
  for (int k = 0; k < TOPK_; ++k) {
    float best = -INFINITY;
    int besti = CHUNK_SZ_;
    for (int i = tid; i < CHUNK_SZ_; i += 256) {
      float x = vals[i];
      if (x > best) { best = x; besti = i; }
    }
    bv[tid] = best; bi[tid] = besti;
    __syncthreads();
    for (int off = 128; off > 0; off >>= 1) {
      if (tid < off) {
        float ov = bv[tid + off]; int oi = bi[tid + off];
        if (ov > bv[tid] || (ov == bv[tid] && oi < bi[tid])) {
          bv[tid] = ov; bi[tid] = oi;
        }
      }
      __syncthreads();
    }
    if (tid == 0) {
      int slot = (b * CHUNKS_ + chunk) * TOPK_ + k;
      cv[slot] = bv[0];
      ci[slot] = base + bi[0];
      if (bi[0] < CHUNK_SZ_) vals[bi[0]] = -INFINITY;
    }
    __syncthreads();
  }
}

// ---------------------------------------------------------------------------
// Kernel 6b: reduce 64 chunks x 10 candidates -> global top-10 per batch.
// ---------------------------------------------------------------------------
__global__ __launch_bounds__(256) void topk_stage2(
    const float* __restrict__ cv, const int* __restrict__ ci,
    int* __restrict__ topk) {
  const int NC = CHUNKS_ * TOPK_;  // 640
  __shared__ float vals[CHUNKS_ * TOPK_];
  __shared__ int gidx[CHUNKS_ * TOPK_];
  __shared__ float bv[256];
  __shared__ int bi[256];
  const int b = blockIdx.x, tid = threadIdx.x;
  for (int i = tid; i < NC; i += 256) {
    vals[i] = cv[(size_t)b * NC + i];
    gidx[i] = ci[(size_t)b * NC + i];
  }
  __syncthreads();
  for (int k = 0; k < TOPK_; ++k) {
    float best = -INFINITY;
    int bslot = NC;
    for (int i = tid; i < NC; i += 256) {
      float x = vals[i];
      if (x > best) { best = x; bslot = i; }
    }
    bv[tid] = best; bi[tid] = bslot;
    __syncthreads();
    for (int off = 128; off > 0; off >>= 1) {
      if (tid < off) {
        float ov = bv[tid + off]; int oi = bi[tid + off];
        if (ov > bv[tid] || (ov == bv[tid] && oi < bi[tid])) {
          bv[tid] = ov; bi[tid] = oi;
        }
      }
      __syncthreads();
    }
    if (tid == 0) {
      int slot = bi[0];
      topk[b * TOPK_ + k] = (slot < NC) ? gidx[slot] : 0;
      if (slot < NC) vals[slot] = -INFINITY;
    }
    __syncthreads();
  }
}

// ---------------------------------------------------------------------------
// Kernel 7: gather word_emd rows -> output [B, K, D]
// ---------------------------------------------------------------------------
__global__ void gather_kernel(const int* __restrict__ topk,
                              const float* __restrict__ w,
                              float* __restrict__ out) {
  const int bk = blockIdx.x;
  const int idx = topk[bk];
  const int t4 = threadIdx.x << 2;
  *(float4*)(out + (size_t)bk * D_ + t4) =
      *(const float4*)(w + (size_t)idx * D_ + t4);
}

extern "C" void kernel_launch(void* const* d_in, const int* in_sizes, int n_in,
                              void* d_out, int out_size, void* d_ws,
                              size_t ws_size, hipStream_t stream) {
  const float* prompt = (const float*)d_in[0];
  const float* enc    = (const float*)d_in[1];
  const float* wemd   = (const float*)d_in[2];
  const float* Wqkv   = (const float*)d_in[3];
  const float* Wproj  = (const float*)d_in[4];
  const float* bproj  = (const float*)d_in[5];
  float* out = (float*)d_out;

  float* ws = (float*)d_ws;
  const size_t QSZ = (size_t)B_ * H_ * L_ * HD_;  // 3,538,944
  float* Vv   = ws;                        // fp32 V
  float* c    = Vv + QSZ;                  // 96*576 = 55,296
  float* t    = c + (size_t)B_ * H_ * L_;  // 6144
  float* s    = t + (size_t)B_ * D_;       // 6144
  float* sim  = s + (size_t)B_ * D_;       // 8*50257 = 402,056
  float* cand_v = sim + (size_t)B_ * V_;   // 8*640 = 5120
  int* cand_i   = (int*)(cand_v + (size_t)B_ * CHUNKS_ * TOPK_);
  int* topk     = cand_i + (size_t)B_ * CHUNKS_ * TOPK_;
  unsigned short* Qhi = (unsigned short*)(topk + B_ * TOPK_ + 64);
  unsigned short* Qlo = Qhi + QSZ;
  unsigned short* Khi = Qlo + QSZ;
  unsigned short* Klo = Khi + QSZ;
  unsigned short* Ahi = Klo + QSZ;
  unsigned short* Alo = Ahi + (size_t)M_QKV * K_QKV;
  unsigned short* Bhi = Alo + (size_t)M_QKV * K_QKV;
  unsigned short* Blo = Bhi + (size_t)N_QKV * K_QKV;

  hipMemsetAsync(c, 0, (size_t)B_ * H_ * L_ * sizeof(float), stream);

  const int NCONV = (M_QKV * K_QKV + N_QKV * K_QKV) / 4;  // 1,327,104
  convert_split<<<(NCONV + 255) / 256, 256, 0, stream>>>(
      prompt, enc, Wqkv, Ahi, Alo, Bhi, Blo);
  qkv_mfma<<<648, 256, 0, stream>>>(
      Ahi, Alo, Bhi, Blo, Qhi, Qlo, Khi, Klo, Vv);
  attn_mfma<<<dim3(9, 96), 256, 0, stream>>>(Qhi, Qlo, Khi, Klo, c);
  cv_kernel<<<96, 64, 0, stream>>>(c, Vv, t);
  proj_kernel<<<8, 768, 0, stream>>>(t, Wproj, bproj, s);
  sim_kernel<<<(V_ + 63) / 64, 256, 0, stream>>>(s, wemd, sim);
  topk_stage1<<<dim3(CHUNKS_, B_), 256, 0, stream>>>(sim, cand_v, cand_i);
  topk_stage2<<<B_, 256, 0, stream>>>(cand_v, cand_i, topk);
  gather_kernel<<<80, 192, 0, stream>>>(topk, wemd, out);
}

// Round 10
// 297.500 us; speedup vs baseline: 1.0556x; 1.0190x over previous
//
#include <hip/hip_runtime.h>
#include <math.h>

#define B_ 8
#define LP_ 64
#define LS_ 512
#define L_ 576
#define D_ 768
#define H_ 12
#define HD_ 64
#define V_ 50257
#define TOPK_ 10
#define CHUNKS_ 64
#define CHUNK_SZ_ 786  // ceil(V_/CHUNKS_); 64*786 = 50304 >= 50257

#define M_QKV 4608   // B_*L_
#define N_QKV 2304   // 3*D_
#define K_QKV 768

typedef __attribute__((ext_vector_type(8))) short bhalf8;
typedef __attribute__((ext_vector_type(4))) float floatx4;

#define GLOAD16(gptr, lptr)                                              \
  __builtin_amdgcn_global_load_lds(                                      \
      (const __attribute__((address_space(1))) unsigned int*)(gptr),     \
      (__attribute__((address_space(3))) unsigned int*)(lptr), 16, 0, 0)

// ---------------------------------------------------------------------------
// bf16 hi/lo split: x = hi + lo, hi = RNE-bf16(x), lo = RNE-bf16(x - hi).
// ---------------------------------------------------------------------------
__device__ inline void bf16split(float f, unsigned short& h, unsigned short& lo) {
  unsigned int u = __float_as_uint(f);
  unsigned short hb = (unsigned short)((u + 0x7FFFu + ((u >> 16) & 1u)) >> 16);
  float hf = __uint_as_float(((unsigned int)hb) << 16);
  float lf = f - hf;
  unsigned int ul = __float_as_uint(lf);
  unsigned short lb = (unsigned short)((ul + 0x7FFFu + ((ul >> 16) & 1u)) >> 16);
  h = hb; lo = lb;
}

// ---------------------------------------------------------------------------
// Kernel 0: build Ahi/Alo (x = concat(prompt,enc)) and Bhi/Blo (= Wqkv).
// ---------------------------------------------------------------------------
__global__ __launch_bounds__(256) void convert_split(
    const float* __restrict__ prompt, const float* __restrict__ enc,
    const float* __restrict__ Wqkv,
    unsigned short* __restrict__ Ahi, unsigned short* __restrict__ Alo,
    unsigned short* __restrict__ Bhi, unsigned short* __restrict__ Blo) {
  const int NA4 = M_QKV * K_QKV / 4;  // 884736
  const int NB4 = N_QKV * K_QKV / 4;  // 442368
  int i = blockIdx.x * 256 + threadIdx.x;
  if (i >= NA4 + NB4) return;
  const float* src;
  unsigned short *dh, *dl;
  int row, c4;
  if (i < NA4) {
    row = i / (K_QKV / 4);
    c4 = (i - row * (K_QKV / 4)) * 4;
    int b = row / L_, ll = row - (row / L_) * L_;
    src = (ll < LP_) ? (prompt + ((size_t)b * LP_ + ll) * D_ + c4)
                     : (enc + ((size_t)b * LS_ + (ll - LP_)) * D_ + c4);
    dh = Ahi + (size_t)row * K_QKV + c4;
    dl = Alo + (size_t)row * K_QKV + c4;
  } else {
    int j = i - NA4;
    row = j / (K_QKV / 4);
    c4 = (j - row * (K_QKV / 4)) * 4;
    src = Wqkv + (size_t)row * K_QKV + c4;
    dh = Bhi + (size_t)row * K_QKV + c4;
    dl = Blo + (size_t)row * K_QKV + c4;
  }
  float4 v = *(const float4*)src;
  ushort4 hv, lv;
  bf16split(v.x, hv.x, lv.x);
  bf16split(v.y, hv.y, lv.y);
  bf16split(v.z, hv.z, lv.z);
  bf16split(v.w, hv.w, lv.w);
  *(ushort4*)dh = hv;
  *(ushort4*)dl = lv;
}

// ---------------------------------------------------------------------------
// Kernel 1: QKV projection, split-bf16 MFMA, fused single K-pass (round-6
// structure, measured best at 110 us).
// ---------------------------------------------------------------------------
__global__ __launch_bounds__(256) void qkv_mfma(
    const unsigned short* __restrict__ Ahi, const unsigned short* __restrict__ Alo,
    const unsigned short* __restrict__ Bhi, const unsigned short* __restrict__ Blo,
    unsigned short* __restrict__ Qhi, unsigned short* __restrict__ Qlo,
    unsigned short* __restrict__ Khi, unsigned short* __restrict__ Klo,
    float* __restrict__ Vv) {
  __shared__ unsigned short Ath[128 * 32];  // 8 KB each
  __shared__ unsigned short Atl[128 * 32];
  __shared__ unsigned short Bth[128 * 32];
  __shared__ unsigned short Btl[128 * 32];
  const int flat = blockIdx.x;
  const int swz = (flat & 7) * 81 + (flat >> 3);  // 648 = 8 XCD x 81
  const int bx = swz % 18, by = swz / 18;
  const int n0 = bx * 128, m0 = by * 128;
  const int tid = threadIdx.x;
  const int l = tid & 63;
  const int w = tid >> 6;
  const int wm = w >> 1, wn = w & 1;

  floatx4 acc[4][4];
#pragma unroll
  for (int i = 0; i < 4; ++i)
#pragma unroll
    for (int j = 0; j < 4; ++j) acc[i][j] = (floatx4){0.f, 0.f, 0.f, 0.f};

  const int r4 = l >> 2;
  const int cs = (l & 3) ^ ((l >> 3) & 3);
  const int lm = l & 15;
  const int lk = l >> 4;
  const int cb = lk ^ ((lm >> 1) & 3);

  for (int kt = 0; kt < 24; ++kt) {
    const int kk0 = kt * 32;
    __syncthreads();
#pragma unroll
    for (int i = 0; i < 2; ++i) {
      const int row = w * 32 + i * 16;
      const size_t ga = (size_t)(m0 + row + r4) * K_QKV + kk0 + cs * 8;
      const size_t gb = (size_t)(n0 + row + r4) * K_QKV + kk0 + cs * 8;
      GLOAD16(Ahi + ga, &Ath[row * 32]);
      GLOAD16(Alo + ga, &Atl[row * 32]);
      GLOAD16(Bhi + gb, &Bth[row * 32]);
      GLOAD16(Blo + gb, &Btl[row * 32]);
    }
    __syncthreads();

    bhalf8 ah[4], al[4], bh8[4], bl8[4];
#pragma unroll
    for (int f = 0; f < 4; ++f) {
      const int ma = wm * 64 + f * 16 + lm;
      const int oa = ma * 32 + cb * 8;
      ah[f] = *(const bhalf8*)&Ath[oa];
      al[f] = *(const bhalf8*)&Atl[oa];
      const int nb = wn * 64 + f * 16 + lm;
      const int ob = nb * 32 + cb * 8;
      bh8[f] = *(const bhalf8*)&Bth[ob];
      bl8[f] = *(const bhalf8*)&Btl[ob];
    }
#pragma unroll
    for (int fm = 0; fm < 4; ++fm)
#pragma unroll
      for (int fn = 0; fn < 4; ++fn) {
        acc[fm][fn] = __builtin_amdgcn_mfma_f32_16x16x32_bf16(
            ah[fm], bh8[fn], acc[fm][fn], 0, 0, 0);
        acc[fm][fn] = __builtin_amdgcn_mfma_f32_16x16x32_bf16(
            al[fm], bh8[fn], acc[fm][fn], 0, 0, 0);
        acc[fm][fn] = __builtin_amdgcn_mfma_f32_16x16x32_bf16(
            ah[fm], bl8[fn], acc[fm][fn], 0, 0, 0);
      }
  }

#pragma unroll
  for (int fm = 0; fm < 4; ++fm) {
#pragma unroll
    for (int fn = 0; fn < 4; ++fn) {
#pragma unroll
      for (int j = 0; j < 4; ++j) {
        int m = m0 + wm * 64 + fm * 16 + lk * 4 + j;
        int n = n0 + wn * 64 + fn * 16 + lm;
        int b = m / L_;
        int ll = m - b * L_;
        int part = n / D_;
        int rem = n - part * D_;
        int h = rem >> 6, e = rem & 63;
        size_t idx = (((size_t)b * H_ + h) * L_ + ll) * HD_ + e;
        float val = acc[fm][fn][j];
        if (part == 2) {
          Vv[idx] = val;
        } else {
          unsigned short hv, lv;
          bf16split(val, hv, lv);
          if (part == 0) { Qhi[idx] = hv; Qlo[idx] = lv; }
          else           { Khi[idx] = hv; Klo[idx] = lv; }
        }
      }
    }
  }
}

// ---------------------------------------------------------------------------
// Kernel 2: attention column sums via split-bf16 MFMA (round-6 single-buffer).
// ---------------------------------------------------------------------------
__global__ __launch_bounds__(256, 2) void attn_mfma(
    const unsigned short* __restrict__ Qhi, const unsigned short* __restrict__ Qlo,
    const unsigned short* __restrict__ Khi, const unsigned short* __restrict__ Klo,
    float* __restrict__ c) {
  __shared__ unsigned short Qh[64 * 64], Ql[64 * 64];  // 8 KB each
  __shared__ unsigned short Kh[64 * 64], Kl[64 * 64];
  __shared__ float c_lds[L_];
  const int qt = blockIdx.x;   // 0..8
  const int bh = blockIdx.y;   // 0..95
  const int tid = threadIdx.x;
  const int w = tid >> 6, l = tid & 63;
  const int lm = l & 15, lk = l >> 4;
  const int r8 = l >> 3;
  const int cs = (l & 7) ^ r8;

  for (int i = tid; i < L_; i += 256) c_lds[i] = 0.f;

  {
    const size_t gbase = ((size_t)bh * L_ + qt * 64) * HD_;
#pragma unroll
    for (int i = 0; i < 2; ++i) {
      int row = w * 16 + i * 8;
      GLOAD16(Qhi + gbase + (size_t)(row + r8) * HD_ + cs * 8, &Qh[row * 64]);
      GLOAD16(Qlo + gbase + (size_t)(row + r8) * HD_ + cs * 8, &Ql[row * 64]);
    }
  }

  floatx4 p[9][4];
#pragma unroll
  for (int kt = 0; kt < 9; ++kt)
#pragma unroll
    for (int fn = 0; fn < 4; ++fn) p[kt][fn] = (floatx4){0.f, 0.f, 0.f, 0.f};
  float zpart[4] = {0.f, 0.f, 0.f, 0.f};

#pragma unroll
  for (int kt = 0; kt < 9; ++kt) {
    __syncthreads();
    const size_t kb = ((size_t)bh * L_ + kt * 64) * HD_;
#pragma unroll
    for (int i = 0; i < 2; ++i) {
      int row = w * 16 + i * 8;
      GLOAD16(Khi + kb + (size_t)(row + r8) * HD_ + cs * 8, &Kh[row * 64]);
      GLOAD16(Klo + kb + (size_t)(row + r8) * HD_ + cs * 8, &Kl[row * 64]);
    }
    __syncthreads();
#pragma unroll
    for (int s = 0; s < 2; ++s) {
      const int ma = w * 16 + lm;
      const int ca = (s * 4 + lk) ^ (ma & 7);
      bhalf8 ah = *(const bhalf8*)&Qh[ma * 64 + ca * 8];
      bhalf8 al = *(const bhalf8*)&Ql[ma * 64 + ca * 8];
#pragma unroll
      for (int fn = 0; fn < 4; ++fn) {
        const int nb = fn * 16 + lm;
        const int cb2 = (s * 4 + lk) ^ (nb & 7);
        bhalf8 bh8 = *(const bhalf8*)&Kh[nb * 64 + cb2 * 8];
        bhalf8 bl8 = *(const bhalf8*)&Kl[nb * 64 + cb2 * 8];
        p[kt][fn] = __builtin_amdgcn_mfma_f32_16x16x32_bf16(ah, bh8, p[kt][fn], 0, 0, 0);
        p[kt][fn] = __builtin_amdgcn_mfma_f32_16x16x32_bf16(al, bh8, p[kt][fn], 0, 0, 0);
        p[kt][fn] = __builtin_amdgcn_mfma_f32_16x16x32_bf16(ah, bl8, p[kt][fn], 0, 0, 0);
      }
    }
#pragma unroll
    for (int fn = 0; fn < 4; ++fn)
#pragma unroll
      for (int j = 0; j < 4; ++j) {
        float e = __expf(p[kt][fn][j] * 0.125f);
        p[kt][fn][j] = e;
        zpart[j] += e;
      }
  }

  float invz[4];
#pragma unroll
  for (int j = 0; j < 4; ++j) {
    float z = zpart[j];
    z += __shfl_xor(z, 1);
    z += __shfl_xor(z, 2);
    z += __shfl_xor(z, 4);
    z += __shfl_xor(z, 8);
    invz[j] = 1.f / z;
  }

#pragma unroll
  for (int kt = 0; kt < 9; ++kt)
#pragma unroll
    for (int fn = 0; fn < 4; ++fn) {
      float cp = p[kt][fn][0] * invz[0] + p[kt][fn][1] * invz[1] +
                 p[kt][fn][2] * invz[2] + p[kt][fn][3] * invz[3];
      cp += __shfl_xor(cp, 16);
      cp += __shfl_xor(cp, 32);
      if (lk == 0) atomicAdd(&c_lds[kt * 64 + fn * 16 + lm], cp);
    }
  __syncthreads();
  for (int i = tid; i < L_; i += 256)
    atomicAdd(&c[(size_t)bh * L_ + i], c_lds[i]);
}

// ---------------------------------------------------------------------------
// Kernel 3: t[b, h*64+e] = sum_k c[b,h,k] * V[b,h,k,e]
// ---------------------------------------------------------------------------
__global__ void cv_kernel(const float* __restrict__ c,
                          const float* __restrict__ Vv,
                          float* __restrict__ t) {
  const int bh = blockIdx.x;
  const int e = threadIdx.x;
  const float* cb = c + (size_t)bh * L_;
  const float* Vb = Vv + (size_t)bh * L_ * HD_;
  float acc = 0.f;
  for (int k = 0; k < L_; ++k) acc = fmaf(cb[k], Vb[(size_t)k * HD_ + e], acc);
  int b = bh / H_, h = bh - (bh / H_) * H_;
  t[(size_t)b * D_ + h * HD_ + e] = acc;
}

// ---------------------------------------------------------------------------
// Kernel 4: s[b,d] = sum_d' t[b,d'] * Wproj[d,d'] + L*bproj[d]
// ---------------------------------------------------------------------------
__global__ __launch_bounds__(768) void proj_kernel(
    const float* __restrict__ t, const float* __restrict__ Wp,
    const float* __restrict__ bp, float* __restrict__ s) {
  __shared__ float tl[768];
  const int b = blockIdx.x, d = threadIdx.x;
  tl[d] = t[(size_t)b * D_ + d];
  __syncthreads();
  float acc = (float)L_ * bp[d];
  const float* wrow = Wp + (size_t)d * D_;
  for (int dp = 0; dp < D_; ++dp) acc = fmaf(tl[dp], wrow[dp], acc);
  s[(size_t)b * D_ + d] = acc;
}

// ---------------------------------------------------------------------------
// Kernel 5: sim[b,v] = sum_d s[b,d] * word_emd[v,d]. Streaming (w has zero
// reuse). Round-9 layout (verified) + latency fixes: 32 rows/block ->
// 1571 blocks (5 LDS-capped blocks/CU, ~20 waves/CU vs 12) and prefetch
// depth 2 (4 KB in flight per wave). Compute per row identical to round 9.
// ---------------------------------------------------------------------------
__global__ __launch_bounds__(256) void sim_kernel(
    const float* __restrict__ s, const float* __restrict__ w,
    float* __restrict__ sim) {
  __shared__ float s2[192 * 36];  // 27.6 KB
  const int tid = threadIdx.x;
  for (int e = tid; e < 6144; e += 256) {
    int b = e / 768;
    int d = e - b * 768;
    int k = d >> 6, pj = d & 63;
    int p = pj >> 2, j = pj & 3;
    s2[(k * 16 + p) * 36 + j * 8 + b] = s[e];
  }
  __syncthreads();

  const int wv = tid >> 6, l = tid & 63;
  const int g = l >> 4, p = l & 15;
  const int base = blockIdx.x * 32 + wv * 8;
  const int rA = base + g, rB = base + g + 4;
  const int cA = (rA < V_) ? rA : (V_ - 1);
  const int cB = (rB < V_) ? rB : (V_ - 1);
  const float* wpA = w + (size_t)cA * D_ + p * 4;
  const float* wpB = w + (size_t)cB * D_ + p * 4;

  float accA[8] = {}, accB[8] = {};
  float4 wa0 = *(const float4*)(wpA);
  float4 wb0 = *(const float4*)(wpB);
  float4 wa1 = *(const float4*)(wpA + 64);
  float4 wb1 = *(const float4*)(wpB + 64);

#pragma unroll
  for (int k = 0; k < 12; ++k) {
    float4 cwa = (k & 1) ? wa1 : wa0;
    float4 cwb = (k & 1) ? wb1 : wb0;
    if (k + 2 < 12) {  // depth-2 prefetch: 2 steps always in flight
      if (k & 1) {
        wa1 = *(const float4*)(wpA + (k + 2) * 64);
        wb1 = *(const float4*)(wpB + (k + 2) * 64);
      } else {
        wa0 = *(const float4*)(wpA + (k + 2) * 64);
        wb0 = *(const float4*)(wpB + (k + 2) * 64);
      }
    }
    const float* sb = &s2[(k * 16 + p) * 36];
    float4 sj[8];
#pragma unroll
    for (int jj = 0; jj < 8; ++jj) sj[jj] = *(const float4*)(sb + jj * 4);
    float ca[4] = {cwa.x, cwa.y, cwa.z, cwa.w};
    float cb[4] = {cwb.x, cwb.y, cwb.z, cwb.w};
#pragma unroll
    for (int j = 0; j < 4; ++j) {
      accA[0] = fmaf(ca[j], sj[2 * j].x, accA[0]);
      accA[1] = fmaf(ca[j], sj[2 * j].y, accA[1]);
      accA[2] = fmaf(ca[j], sj[2 * j].z, accA[2]);
      accA[3] = fmaf(ca[j], sj[2 * j].w, accA[3]);
      accA[4] = fmaf(ca[j], sj[2 * j + 1].x, accA[4]);
      accA[5] = fmaf(ca[j], sj[2 * j + 1].y, accA[5]);
      accA[6] = fmaf(ca[j], sj[2 * j + 1].z, accA[6]);
      accA[7] = fmaf(ca[j], sj[2 * j + 1].w, accA[7]);
      accB[0] = fmaf(cb[j], sj[2 * j].x, accB[0]);
      accB[1] = fmaf(cb[j], sj[2 * j].y, accB[1]);
      accB[2] = fmaf(cb[j], sj[2 * j].z, accB[2]);
      accB[3] = fmaf(cb[j], sj[2 * j].w, accB[3]);
      accB[4] = fmaf(cb[j], sj[2 * j + 1].x, accB[4]);
      accB[5] = fmaf(cb[j], sj[2 * j + 1].y, accB[5]);
      accB[6] = fmaf(cb[j], sj[2 * j + 1].z, accB[6]);
      accB[7] = fmaf(cb[j], sj[2 * j + 1].w, accB[7]);
    }
  }

  // reduce over the 16 lanes of the group (xor masks 1,2,4,8 stay in-group)
#pragma unroll
  for (int off = 1; off < 16; off <<= 1) {
#pragma unroll
    for (int b = 0; b < 8; ++b) {
      accA[b] += __shfl_xor(accA[b], off);
      accB[b] += __shfl_xor(accB[b], off);
    }
  }
  if (p == 0) {
#pragma unroll
    for (int b = 0; b < 8; ++b) {
      if (rA < V_) sim[(size_t)b * V_ + rA] = accA[b];
      if (rB < V_) sim[(size_t)b * V_ + rB] = accB[b];
    }
  }
}

// ---------------------------------------------------------------------------
// Kernel 6a: per-chunk local top-10.
// ---------------------------------------------------------------------------
__global__ __launch_bounds__(256) void topk_stage1(
    const float* __restrict__ sim, float* __restrict__ cv,
    int* __restrict__ ci) {
  __shared__ float vals[CHUNK_SZ_];
  __shared__ float bv[256];
  __shared__ int bi[256];
  const int chunk = blockIdx.x, b = blockIdx.y, tid = threadIdx.x;
  const int base = chunk * CHUNK_SZ_;
  const float* row = sim + (size_t)b * V_;
  for (int i = tid; i < CHUNK_SZ_; i += 256) {
    int v = base + i;
    vals[i] = (v < V_) ? row[v] : -INFINITY;
  }
  __syncthreads();
  for (int k = 0; k < TOPK_; ++k) {
    float best = -INFINITY;
    int besti = CHUNK_SZ_;
    for (int i = tid; i < CHUNK_SZ_; i += 256) {
      float x = vals[i];
      if (x > best) { best = x; besti = i; }
    }
    bv[tid] = best; bi[tid] = besti;
    __syncthreads();
    for (int off = 128; off > 0; off >>= 1) {
      if (tid < off) {
        float ov = bv[tid + off]; int oi = bi[tid + off];
        if (ov > bv[tid] || (ov == bv[tid] && oi < bi[tid])) {
          bv[tid] = ov; bi[tid] = oi;
        }
      }
      __syncthreads();
    }
    if (tid == 0) {
      int slot = (b * CHUNKS_ + chunk) * TOPK_ + k;
      cv[slot] = bv[0];
      ci[slot] = base + bi[0];
      if (bi[0] < CHUNK_SZ_) vals[bi[0]] = -INFINITY;
    }
    __syncthreads();
  }
}

// ---------------------------------------------------------------------------
// Kernel 6b: reduce 64 chunks x 10 candidates -> global top-10 per batch.
// ---------------------------------------------------------------------------
__global__ __launch_bounds__(256) void topk_stage2(
    const float* __restrict__ cv, const int* __restrict__ ci,
    int* __restrict__ topk) {
  const int NC = CHUNKS_ * TOPK_;  // 640
  __shared__ float vals[CHUNKS_ * TOPK_];
  __shared__ int gidx[CHUNKS_ * TOPK_];
  __shared__ float bv[256];
  __shared__ int bi[256];
  const int b = blockIdx.x, tid = threadIdx.x;
  for (int i = tid; i < NC; i += 256) {
    vals[i] = cv[(size_t)b * NC + i];
    gidx[i] = ci[(size_t)b * NC + i];
  }
  __syncthreads();
  for (int k = 0; k < TOPK_; ++k) {
    float best = -INFINITY;
    int bslot = NC;
    for (int i = tid; i < NC; i += 256) {
      float x = vals[i];
      if (x > best) { best = x; bslot = i; }
    }
    bv[tid] = best; bi[tid] = bslot;
    __syncthreads();
    for (int off = 128; off > 0; off >>= 1) {
      if (tid < off) {
        float ov = bv[tid + off]; int oi = bi[tid + off];
        if (ov > bv[tid] || (ov == bv[tid] && oi < bi[tid])) {
          bv[tid] = ov; bi[tid] = oi;
        }
      }
      __syncthreads();
    }
    if (tid == 0) {
      int slot = bi[0];
      topk[b * TOPK_ + k] = (slot < NC) ? gidx[slot] : 0;
      if (slot < NC) vals[slot] = -INFINITY;
    }
    __syncthreads();
  }
}

// ---------------------------------------------------------------------------
// Kernel 7: gather word_emd rows -> output [B, K, D]
// ---------------------------------------------------------------------------
__global__ void gather_kernel(const int* __restrict__ topk,
                              const float* __restrict__ w,
                              float* __restrict__ out) {
  const int bk = blockIdx.x;
  const int idx = topk[bk];
  const int t4 = threadIdx.x << 2;
  *(float4*)(out + (size_t)bk * D_ + t4) =
      *(const float4*)(w + (size_t)idx * D_ + t4);
}

extern "C" void kernel_launch(void* const* d_in, const int* in_sizes, int n_in,
                              void* d_out, int out_size, void* d_ws,
                              size_t ws_size, hipStream_t stream) {
  const float* prompt = (const float*)d_in[0];
  const float* enc    = (const float*)d_in[1];
  const float* wemd   = (const float*)d_in[2];
  const float* Wqkv   = (const float*)d_in[3];
  const float* Wproj  = (const float*)d_in[4];
  const float* bproj  = (const float*)d_in[5];
  float* out = (float*)d_out;

  float* ws = (float*)d_ws;
  const size_t QSZ = (size_t)B_ * H_ * L_ * HD_;  // 3,538,944
  float* Vv   = ws;                        // fp32 V
  float* c    = Vv + QSZ;                  // 96*576 = 55,296
  float* t    = c + (size_t)B_ * H_ * L_;  // 6144
  float* s    = t + (size_t)B_ * D_;       // 6144
  float* sim  = s + (size_t)B_ * D_;       // 8*50257 = 402,056
  float* cand_v = sim + (size_t)B_ * V_;   // 8*640 = 5120
  int* cand_i   = (int*)(cand_v + (size_t)B_ * CHUNKS_ * TOPK_);
  int* topk     = cand_i + (size_t)B_ * CHUNKS_ * TOPK_;
  unsigned short* Qhi = (unsigned short*)(topk + B_ * TOPK_ + 64);
  unsigned short* Qlo = Qhi + QSZ;
  unsigned short* Khi = Qlo + QSZ;
  unsigned short* Klo = Khi + QSZ;
  unsigned short* Ahi = Klo + QSZ;
  unsigned short* Alo = Ahi + (size_t)M_QKV * K_QKV;
  unsigned short* Bhi = Alo + (size_t)M_QKV * K_QKV;
  unsigned short* Blo = Bhi + (size_t)N_QKV * K_QKV;

  hipMemsetAsync(c, 0, (size_t)B_ * H_ * L_ * sizeof(float), stream);

  const int NCONV = (M_QKV * K_QKV + N_QKV * K_QKV) / 4;  // 1,327,104
  convert_split<<<(NCONV + 255) / 256, 256, 0, stream>>>(
      prompt, enc, Wqkv, Ahi, Alo, Bhi, Blo);
  qkv_mfma<<<648, 256, 0, stream>>>(
      Ahi, Alo, Bhi, Blo, Qhi, Qlo, Khi, Klo, Vv);
  attn_mfma<<<dim3(9, 96), 256, 0, stream>>>(Qhi, Qlo, Khi, Klo, c);
  cv_kernel<<<96, 64, 0, stream>>>(c, Vv, t);
  proj_kernel<<<8, 768, 0, stream>>>(t, Wproj, bproj, s);
  sim_kernel<<<(V_ + 31) / 32, 256, 0, stream>>>(s, wemd, sim);
  topk_stage1<<<dim3(CHUNKS_, B_), 256, 0, stream>>>(sim, cand_v, cand_i);
  topk_stage2<<<B_, 256, 0, stream>>>(cand_v, cand_i, topk);
  gather_kernel<<<80, 192, 0, stream>>>(topk, wemd, out);
}